// Round 9
// baseline (1151.147 us; speedup 1.0000x reference)
//
#include <hip/hip_runtime.h>

#define BB 8
#define NN 2048
#define WGS 512
#define GRID 512
#define WG_PER_B (GRID / BB)                 // 64 WGs per batch
#define ROWS_PER_WG (NN / WG_PER_B)          // 32
#define NWAVES (WGS / 64)                    // 8
#define ROWS_PER_WAVE (ROWS_PER_WG / NWAVES) // 4
#define CHUNKS (NN / 64)                     // 32
#define MAX_ITER 50

// eps = 0.005; work in log2 domain: SCL = log2(e)/eps
constexpr float SCL       = 288.5390081777927f;
constexpr float LN2f      = 0.6931471805599453f;
constexpr float EPSf      = 0.005f;
constexpr float EPS_LOGMU = -0.03812309493079699f; // 0.005 * (-ln 2048)

__device__ __forceinline__ float fexp2(float x) { return __builtin_amdgcn_exp2f(x); }
__device__ __forceinline__ float flog2(float x) { return __builtin_amdgcn_logf(x); }

__device__ __forceinline__ float wmax(float v) {
  #pragma unroll
  for (int d = 32; d; d >>= 1) v = fmaxf(v, __shfl_xor(v, d, 64));
  return v;
}
__device__ __forceinline__ float wsum(float v) {
  #pragma unroll
  for (int d = 32; d; d >>= 1) v += __shfl_xor(v, d, 64);
  return v;
}

// One-time prep: pack {x,y,z,|p|^2} per point for both clouds.
// Jp[0 .. BB*NN)          = pcs1 packed
// Jp[BB*NN .. 2*BB*NN)    = pcs2 packed
__global__ __launch_bounds__(256) void pack_pts(
    const float* __restrict__ pcs1, const float* __restrict__ pcs2,
    float4* __restrict__ Jp)
{
  int idx = blockIdx.x * 256 + threadIdx.x;
  if (idx >= 2 * BB * NN) return;
  const float* s = (idx < BB * NN) ? (pcs1 + 3 * (size_t)idx)
                                   : (pcs2 + 3 * (size_t)(idx - BB * NN));
  float x = s[0], y = s[1], z = s[2];
  Jp[idx] = make_float4(x, y, z, fmaf(x, x, fmaf(y, y, z * z)));
}

// One half-iteration: potOut_i = eps*log_mu - eps*lse_j((potIn_j - C_ij)/eps)
// rowsPack/colsPack are {x,y,z,qq}. ZERO_POT: treat potIn as all-zero (iter 0).
// Cross-launch visibility via kernel boundaries on the stream — no inter-WG sync.
template <bool ZERO_POT>
__global__ __launch_bounds__(WGS) void half_iter(
    const float4* __restrict__ rowsPack, const float4* __restrict__ colsPack,
    const float* __restrict__ potIn, float* __restrict__ potOut)
{
  __shared__ float4 J[NN];   // {x,y,z, (pot_j - |q_j|^2)*SCL}
  const int wg = blockIdx.x, tid = threadIdx.x;
  const int b = wg / WG_PER_B, sub = wg % WG_PER_B;
  const int lane = tid & 63, wv = tid >> 6;

  const float4* C  = colsPack + (size_t)b * NN;
  const float*  PI = potIn + b * NN;
  #pragma unroll
  for (int j = tid; j < NN; j += WGS) {
    float4 q = C[j];
    float pot = ZERO_POT ? 0.f : PI[j];
    q.w = (pot - q.w) * SCL;
    J[j] = q;
  }
  __syncthreads();

  const int i0 = sub * ROWS_PER_WG + wv * ROWS_PER_WAVE;
  const float4* R = rowsPack + (size_t)b * NN + i0;
  const float4 p0 = R[0], p1 = R[1], p2 = R[2], p3 = R[3];
  const float X0x=2.f*SCL*p0.x, X0y=2.f*SCL*p0.y, X0z=2.f*SCL*p0.z, B0=-SCL*p0.w;
  const float X1x=2.f*SCL*p1.x, X1y=2.f*SCL*p1.y, X1z=2.f*SCL*p1.z, B1=-SCL*p1.w;
  const float X2x=2.f*SCL*p2.x, X2y=2.f*SCL*p2.y, X2z=2.f*SCL*p2.z, B2=-SCL*p2.w;
  const float X3x=2.f*SCL*p3.x, X3y=2.f*SCL*p3.y, X3z=2.f*SCL*p3.z, B3=-SCL*p3.w;

  // pass 1: row maxima (unroll capped at 4: full unroll clusters 32 b128
  // loads -> 128 live VGPRs -> scratch spill, the rounds-1..5 killer)
  float m0 = -3.4e38f, m1 = -3.4e38f, m2 = -3.4e38f, m3 = -3.4e38f;
  #pragma unroll 4
  for (int k = 0; k < CHUNKS; ++k) {
    float4 q = J[k * 64 + lane];
    m0 = fmaxf(m0, fmaf(X0x, q.x, fmaf(X0y, q.y, fmaf(X0z, q.z, q.w))));
    m1 = fmaxf(m1, fmaf(X1x, q.x, fmaf(X1y, q.y, fmaf(X1z, q.z, q.w))));
    m2 = fmaxf(m2, fmaf(X2x, q.x, fmaf(X2y, q.y, fmaf(X2z, q.z, q.w))));
    m3 = fmaxf(m3, fmaf(X3x, q.x, fmaf(X3y, q.y, fmaf(X3z, q.z, q.w))));
  }
  const float M0 = wmax(m0), M1 = wmax(m1), M2 = wmax(m2), M3 = wmax(m3);

  // pass 2: recompute T, accumulate exp2
  float s0 = 0.f, s1 = 0.f, s2 = 0.f, s3 = 0.f;
  #pragma unroll 4
  for (int k = 0; k < CHUNKS; ++k) {
    float4 q = J[k * 64 + lane];
    s0 += fexp2(fmaf(X0x, q.x, fmaf(X0y, q.y, fmaf(X0z, q.z, q.w - M0))));
    s1 += fexp2(fmaf(X1x, q.x, fmaf(X1y, q.y, fmaf(X1z, q.z, q.w - M1))));
    s2 += fexp2(fmaf(X2x, q.x, fmaf(X2y, q.y, fmaf(X2z, q.z, q.w - M2))));
    s3 += fexp2(fmaf(X3x, q.x, fmaf(X3y, q.y, fmaf(X3z, q.z, q.w - M3))));
  }
  const float S0 = wsum(s0), S1 = wsum(s1), S2 = wsum(s2), S3 = wsum(s3);
  if (lane == 0) {
    float* PO = potOut + b * NN + i0;
    PO[0] = EPS_LOGMU - EPSf*LN2f*(B0 + M0 + flog2(S0));
    PO[1] = EPS_LOGMU - EPSf*LN2f*(B1 + M1 + flog2(S1));
    PO[2] = EPS_LOGMU - EPSf*LN2f*(B2 + M2 + flog2(S2));
    PO[3] = EPS_LOGMU - EPSf*LN2f*(B3 + M3 + flog2(S3));
  }
}

// dist_i = N * sum_j exp2((f_i + g_j - C_ij)*SCL) * C_ij ; per-WG partial
// sums of sqrt(dist) -> partials[wg].
__global__ __launch_bounds__(WGS) void emd_finalize(
    const float4* __restrict__ rowsPack, const float4* __restrict__ colsPack,
    const float* __restrict__ fArr, const float* __restrict__ gArr,
    float* __restrict__ partials)
{
  __shared__ float4 J[NN];   // {x,y,z, g_j*SCL}
  __shared__ float red[NWAVES];
  const int wg = blockIdx.x, tid = threadIdx.x;
  const int b = wg / WG_PER_B, sub = wg % WG_PER_B;
  const int lane = tid & 63, wv = tid >> 6;

  const float4* C = colsPack + (size_t)b * NN;
  const float*  G = gArr + b * NN;
  #pragma unroll
  for (int j = tid; j < NN; j += WGS) {
    float4 q = C[j];
    q.w = G[j] * SCL;
    J[j] = q;
  }
  __syncthreads();

  const int i0 = sub * ROWS_PER_WG + wv * ROWS_PER_WAVE;
  const float4* R = rowsPack + (size_t)b * NN;
  const float*  F = fArr + b * NN;
  float part = 0.f;
  #pragma unroll 1
  for (int r = 0; r < ROWS_PER_WAVE; ++r) {
    const int i = i0 + r;
    const float4 p = R[i];
    const float Fi = F[i] * SCL;
    float a0 = 0.f, a1 = 0.f;
    #pragma unroll 2
    for (int k = 0; k < CHUNKS; k += 2) {
      float4 qa = J[k * 64 + lane];
      float4 qb = J[(k + 1) * 64 + lane];
      float dxa = p.x - qa.x, dya = p.y - qa.y, dza = p.z - qa.z;
      float ca = fmaf(dxa, dxa, fmaf(dya, dya, dza * dza));
      a0 = fmaf(fexp2(fmaf(-SCL, ca, Fi + qa.w)), ca, a0);
      float dxb = p.x - qb.x, dyb = p.y - qb.y, dzb = p.z - qb.z;
      float cb = fmaf(dxb, dxb, fmaf(dyb, dyb, dzb * dzb));
      a1 = fmaf(fexp2(fmaf(-SCL, cb, Fi + qb.w)), cb, a1);
    }
    float lacc = wsum(a0 + a1);
    if (lane == 0) part += sqrtf((float)NN * lacc + 1e-12f);
  }
  if (lane == 0) red[wv] = part;
  __syncthreads();
  if (tid == 0) {
    float s = 0.f;
    #pragma unroll
    for (int w = 0; w < NWAVES; ++w) s += red[w];
    partials[wg] = s;
  }
}

// Deterministic GRID-way reduction -> mean.
__global__ __launch_bounds__(GRID) void emd_reduce(
    const float* __restrict__ partials, float* __restrict__ out)
{
  __shared__ float sb[GRID / 64];
  const int tid = threadIdx.x;
  float v = wsum(partials[tid]);
  if ((tid & 63) == 0) sb[tid >> 6] = v;
  __syncthreads();
  if (tid == 0) {
    float s = 0.f;
    #pragma unroll
    for (int w = 0; w < GRID / 64; ++w) s += sb[w];
    out[0] = s * (1.f / 16384.f);
  }
}

extern "C" void kernel_launch(void* const* d_in, const int* in_sizes, int n_in,
                              void* d_out, int out_size, void* d_ws, size_t ws_size,
                              hipStream_t stream) {
  const float* pcs1 = (const float*)d_in[0];
  const float* pcs2 = (const float*)d_in[1];
  float* out      = (float*)d_out;
  float* fArr     = (float*)d_ws;                       // BB*NN f32
  float* gArr     = fArr + BB * NN;                     // BB*NN f32
  float* partials = gArr + BB * NN;                     // GRID f32
  float4* Jpack   = (float4*)((char*)d_ws + 256 * 1024);// 2*BB*NN float4 (16B-aligned)
  const float4* P1 = Jpack;
  const float4* P2 = Jpack + BB * NN;

  pack_pts<<<(2 * BB * NN + 255) / 256, 256, 0, stream>>>(pcs1, pcs2, Jpack);

  // iter 0 f-update reads g==0 (templated; no memset dispatch needed)
  half_iter<true ><<<GRID, WGS, 0, stream>>>(P1, P2, gArr, fArr);
  half_iter<false><<<GRID, WGS, 0, stream>>>(P2, P1, fArr, gArr);
  for (int it = 1; it < MAX_ITER; ++it) {
    half_iter<false><<<GRID, WGS, 0, stream>>>(P1, P2, gArr, fArr);
    half_iter<false><<<GRID, WGS, 0, stream>>>(P2, P1, fArr, gArr);
  }
  emd_finalize<<<GRID, WGS, 0, stream>>>(P1, P2, fArr, gArr, partials);
  emd_reduce<<<1, GRID, 0, stream>>>(partials, out);
}

// Round 10
// 1128.013 us; speedup vs baseline: 1.0205x; 1.0205x over previous
//
#include <hip/hip_runtime.h>

#define BB 8
#define NN 2048
#define WGS 1024
#define GRID 256
#define WG_PER_B (GRID / BB)                 // 32 WGs per batch
#define ROWS_PER_WG (NN / WG_PER_B)          // 64
#define NWAVES (WGS / 64)                    // 16
#define ROWS_PER_WAVE (ROWS_PER_WG / NWAVES) // 4
#define CHUNKS (NN / 64)                     // 32
#define MAX_ITER 50

// eps = 0.005; work in log2 domain: SCL = log2(e)/eps
constexpr float SCL       = 288.5390081777927f;
constexpr float LN2f      = 0.6931471805599453f;
constexpr float EPSf      = 0.005f;
constexpr float EPS_LOGMU = -0.03812309493079699f; // 0.005 * (-ln 2048)

__device__ __forceinline__ float fexp2(float x) { return __builtin_amdgcn_exp2f(x); }
__device__ __forceinline__ float flog2(float x) { return __builtin_amdgcn_logf(x); }

// monotone float<->int map so atomicMax(int) orders floats (incl. negatives)
__device__ __forceinline__ int   fkey(float x) { int i = __float_as_int(x); return i >= 0 ? i : i ^ 0x7fffffff; }
__device__ __forceinline__ float funkey(int k) { return __int_as_float(k >= 0 ? k : k ^ 0x7fffffff); }

__device__ __forceinline__ float wsum(float v) {
  #pragma unroll
  for (int d = 32; d; d >>= 1) v += __shfl_xor(v, d, 64);
  return v;
}

// One-time prep: pack {x,y,z,|p|^2} per point for both clouds; init the 32
// per-batch max slots (4 groups of 8: maxF[0],maxF[1],maxG[0],maxG[1]).
__global__ __launch_bounds__(256) void pack_pts(
    const float* __restrict__ pcs1, const float* __restrict__ pcs2,
    float4* __restrict__ Jp, int* __restrict__ slots)
{
  int idx = blockIdx.x * 256 + threadIdx.x;
  if (idx < 32) slots[idx] = fkey(-3.0e38f);
  if (idx >= 2 * BB * NN) return;
  const float* s = (idx < BB * NN) ? (pcs1 + 3 * (size_t)idx)
                                   : (pcs2 + 3 * (size_t)(idx - BB * NN));
  float x = s[0], y = s[1], z = s[2];
  Jp[idx] = make_float4(x, y, z, fmaf(x, x, fmaf(y, y, z * z)));
}

// One half-iteration, SINGLE PASS: the per-row max pass is replaced by a
// per-batch shift M = max_j potIn_j * SCL (computed by the previous dispatch
// via atomicMax). Exponent E = (pot_j - C_ij)*SCL - M <= 0 by construction;
// E >= rowmax - (pot spread + nn-dist)*SCL, well inside fp32 range for these
// clouds; fmaxf(S,1e-37) backstops underflow as a visible error, not inf.
// maxOutSlot[b] collects max_i potOut_i for the NEXT dispatch; maxResetSlot
// is the opposite-parity slot of the same family (last read one dispatch ago).
template <bool ZERO_POT>
__global__ __launch_bounds__(WGS)
__attribute__((amdgpu_waves_per_eu(4, 4)))
void half_iter(
    const float4* __restrict__ rowsPack, const float4* __restrict__ colsPack,
    const float* __restrict__ potIn, float* __restrict__ potOut,
    const int* __restrict__ maxInSlot, int* __restrict__ maxOutSlot,
    int* __restrict__ maxResetSlot)
{
  __shared__ float4 J[NN];   // {x,y,z, (pot_j - |q_j|^2)*SCL - M}
  __shared__ float red[NWAVES];
  const int wg = blockIdx.x, tid = threadIdx.x;
  const int b = wg / WG_PER_B, sub = wg % WG_PER_B;
  const int lane = tid & 63, wv = tid >> 6;

  if (sub == 0 && tid == WGS - 1)
    __hip_atomic_store(maxResetSlot + b, fkey(-3.0e38f),
                       __ATOMIC_RELAXED, __HIP_MEMORY_SCOPE_AGENT);

  const float M = ZERO_POT ? 0.f
      : funkey(__hip_atomic_load(maxInSlot + b, __ATOMIC_RELAXED,
                                 __HIP_MEMORY_SCOPE_AGENT)) * SCL;

  const float4* C  = colsPack + (size_t)b * NN;
  const float*  PI = potIn + b * NN;
  #pragma unroll
  for (int j = tid; j < NN; j += WGS) {
    float4 q = C[j];
    float pot = ZERO_POT ? 0.f : PI[j];
    q.w = fmaf(pot - q.w, SCL, -M);
    J[j] = q;
  }
  __syncthreads();

  const int i0 = sub * ROWS_PER_WG + wv * ROWS_PER_WAVE;
  const float4* R = rowsPack + (size_t)b * NN + i0;
  const float4 p0 = R[0], p1 = R[1], p2 = R[2], p3 = R[3];
  const float X0x=2.f*SCL*p0.x, X0y=2.f*SCL*p0.y, X0z=2.f*SCL*p0.z, B0=-SCL*p0.w;
  const float X1x=2.f*SCL*p1.x, X1y=2.f*SCL*p1.y, X1z=2.f*SCL*p1.z, B1=-SCL*p1.w;
  const float X2x=2.f*SCL*p2.x, X2y=2.f*SCL*p2.y, X2z=2.f*SCL*p2.z, B2=-SCL*p2.w;
  const float X3x=2.f*SCL*p3.x, X3y=2.f*SCL*p3.y, X3z=2.f*SCL*p3.z, B3=-SCL*p3.w;

  // single pass: E_rj = B_r + q.w + X_r·q ; s_r += 2^E  (5 main ops + 1 trans)
  // unroll capped at 4: full unroll clusters 32 b128 loads -> spill (r1..r5)
  float s0 = 0.f, s1 = 0.f, s2 = 0.f, s3 = 0.f;
  #pragma unroll 4
  for (int k = 0; k < CHUNKS; ++k) {
    float4 q = J[k * 64 + lane];
    s0 += fexp2(fmaf(X0x, q.x, fmaf(X0y, q.y, fmaf(X0z, q.z, q.w + B0))));
    s1 += fexp2(fmaf(X1x, q.x, fmaf(X1y, q.y, fmaf(X1z, q.z, q.w + B1))));
    s2 += fexp2(fmaf(X2x, q.x, fmaf(X2y, q.y, fmaf(X2z, q.z, q.w + B2))));
    s3 += fexp2(fmaf(X3x, q.x, fmaf(X3y, q.y, fmaf(X3z, q.z, q.w + B3))));
  }
  const float S0 = wsum(s0), S1 = wsum(s1), S2 = wsum(s2), S3 = wsum(s3);
  if (lane == 0) {
    const float o0 = EPS_LOGMU - EPSf*LN2f*(M + flog2(fmaxf(S0, 1e-37f)));
    const float o1 = EPS_LOGMU - EPSf*LN2f*(M + flog2(fmaxf(S1, 1e-37f)));
    const float o2 = EPS_LOGMU - EPSf*LN2f*(M + flog2(fmaxf(S2, 1e-37f)));
    const float o3 = EPS_LOGMU - EPSf*LN2f*(M + flog2(fmaxf(S3, 1e-37f)));
    float* PO = potOut + b * NN + i0;
    PO[0] = o0; PO[1] = o1; PO[2] = o2; PO[3] = o3;
    red[wv] = fmaxf(fmaxf(o0, o1), fmaxf(o2, o3));
  }
  __syncthreads();
  if (tid == 0) {
    float mx = red[0];
    #pragma unroll
    for (int w = 1; w < NWAVES; ++w) mx = fmaxf(mx, red[w]);
    atomicMax(maxOutSlot + b, fkey(mx));   // one far-atomic per WG
  }
}

// dist_i = N * sum_j exp2((f_i + g_j - C_ij)*SCL) * C_ij ; per-WG partial
// sums of sqrt(dist) -> partials[wg].
__global__ __launch_bounds__(WGS)
__attribute__((amdgpu_waves_per_eu(4, 4)))
void emd_finalize(
    const float4* __restrict__ rowsPack, const float4* __restrict__ colsPack,
    const float* __restrict__ fArr, const float* __restrict__ gArr,
    float* __restrict__ partials)
{
  __shared__ float4 J[NN];   // {x,y,z, g_j*SCL}
  __shared__ float red[NWAVES];
  const int wg = blockIdx.x, tid = threadIdx.x;
  const int b = wg / WG_PER_B, sub = wg % WG_PER_B;
  const int lane = tid & 63, wv = tid >> 6;

  const float4* C = colsPack + (size_t)b * NN;
  const float*  G = gArr + b * NN;
  #pragma unroll
  for (int j = tid; j < NN; j += WGS) {
    float4 q = C[j];
    q.w = G[j] * SCL;
    J[j] = q;
  }
  __syncthreads();

  const int i0 = sub * ROWS_PER_WG + wv * ROWS_PER_WAVE;
  const float4* R = rowsPack + (size_t)b * NN;
  const float*  F = fArr + b * NN;
  float part = 0.f;
  #pragma unroll 1
  for (int r = 0; r < ROWS_PER_WAVE; ++r) {
    const int i = i0 + r;
    const float4 p = R[i];
    const float Fi = F[i] * SCL;
    float a0 = 0.f, a1 = 0.f;
    #pragma unroll 2
    for (int k = 0; k < CHUNKS; k += 2) {
      float4 qa = J[k * 64 + lane];
      float4 qb = J[(k + 1) * 64 + lane];
      float dxa = p.x - qa.x, dya = p.y - qa.y, dza = p.z - qa.z;
      float ca = fmaf(dxa, dxa, fmaf(dya, dya, dza * dza));
      a0 = fmaf(fexp2(fmaf(-SCL, ca, Fi + qa.w)), ca, a0);
      float dxb = p.x - qb.x, dyb = p.y - qb.y, dzb = p.z - qb.z;
      float cb = fmaf(dxb, dxb, fmaf(dyb, dyb, dzb * dzb));
      a1 = fmaf(fexp2(fmaf(-SCL, cb, Fi + qb.w)), cb, a1);
    }
    float lacc = wsum(a0 + a1);
    if (lane == 0) part += sqrtf((float)NN * lacc + 1e-12f);
  }
  if (lane == 0) red[wv] = part;
  __syncthreads();
  if (tid == 0) {
    float s = 0.f;
    #pragma unroll
    for (int w = 0; w < NWAVES; ++w) s += red[w];
    partials[wg] = s;
  }
}

// Deterministic GRID-way reduction -> mean.
__global__ __launch_bounds__(GRID) void emd_reduce(
    const float* __restrict__ partials, float* __restrict__ out)
{
  __shared__ float sb[GRID / 64];
  const int tid = threadIdx.x;
  float v = wsum(partials[tid]);
  if ((tid & 63) == 0) sb[tid >> 6] = v;
  __syncthreads();
  if (tid == 0) {
    float s = 0.f;
    #pragma unroll
    for (int w = 0; w < GRID / 64; ++w) s += sb[w];
    out[0] = s * (1.f / 16384.f);
  }
}

extern "C" void kernel_launch(void* const* d_in, const int* in_sizes, int n_in,
                              void* d_out, int out_size, void* d_ws, size_t ws_size,
                              hipStream_t stream) {
  const float* pcs1 = (const float*)d_in[0];
  const float* pcs2 = (const float*)d_in[1];
  float* out      = (float*)d_out;
  float* fArr     = (float*)d_ws;                        // BB*NN f32
  float* gArr     = fArr + BB * NN;                      // BB*NN f32
  float* partials = gArr + BB * NN;                      // GRID f32
  int*   slots    = (int*)(partials + GRID);             // 32 ints
  int*   MF[2]    = { slots,      slots + 8  };          // maxF parity slots
  int*   MG[2]    = { slots + 16, slots + 24 };          // maxG parity slots
  float4* Jpack   = (float4*)((char*)d_ws + 256 * 1024); // 2*BB*NN float4
  const float4* P1 = Jpack;
  const float4* P2 = Jpack + BB * NN;

  pack_pts<<<(2 * BB * NN + 255) / 256, 256, 0, stream>>>(pcs1, pcs2, Jpack, slots);

  // t=0: f reads g==0 (M=0), writes MF[0], resets MF[1]; g reads MF[0],
  // writes MG[0], resets MG[1]. Slot written at t is read at t+1 and reset
  // one dispatch after its last read — always kernel-boundary ordered.
  half_iter<true ><<<GRID, WGS, 0, stream>>>(P1, P2, gArr, fArr, nullptr, MF[0], MF[1]);
  half_iter<false><<<GRID, WGS, 0, stream>>>(P2, P1, fArr, gArr, MF[0], MG[0], MG[1]);
  for (int t = 1; t < MAX_ITER; ++t) {
    const int p = t & 1, q = p ^ 1;
    half_iter<false><<<GRID, WGS, 0, stream>>>(P1, P2, gArr, fArr, MG[q], MF[p], MF[q]);
    half_iter<false><<<GRID, WGS, 0, stream>>>(P2, P1, fArr, gArr, MF[p], MG[p], MG[q]);
  }
  emd_finalize<<<GRID, WGS, 0, stream>>>(P1, P2, fArr, gArr, partials);
  emd_reduce<<<1, GRID, 0, stream>>>(partials, out);
}